// Round 8
// baseline (443.565 us; speedup 1.0000x reference)
//
#include <hip/hip_runtime.h>
#include <stdint.h>

// Problem constants (from reference):
#define B_ROWS   2048
#define N_COLS   150000
#define NSTRIPS  128
#define CHUNK    128
#define NCHUNK   1172                             // ceil(150000/128), tail has 112 cols
#define ROWG     16                               // 2048/128 row groups

#define NEG_HUGE (-3.0e38f)
// Gumbel hard bounds: u in [tiny, 1-2^-23] -> g in [-4.46966, +15.94238].
#define G_SPAN_HARD  20.6f      // hard winner bound incl. mfma split slack
#define G_MAX_MARGIN 15.944f    // max achievable gumbel + logf-err margin
// Certified |s_canon - s_mfma_nat| <= ||q||2 * ||e||2 * EPS_B (invariant under
// the log2e pre-scaling: scaled-space error x ln2 == unscaled bound)
#define EPS_B        2.0e-4f
#define G_FILTER_SLACK 3e-5f    // f32 tie safety on the per-column gumbel filter

#define LOG2E_F 1.44269504088896340736f
#define LN2_F   0.69314718055994530942f

#if __has_builtin(__builtin_amdgcn_exp2f)
#define EXP2F(x) __builtin_amdgcn_exp2f(x)
#else
#define EXP2F(x) exp2f(x)
#endif

// ws layout (float offsets)
#define WS_MPART 0                                       // [B_ROWS][NSTRIPS] (log2-scaled)
#define WS_ZPART (B_ROWS * NSTRIPS)                      // [B_ROWS][NSTRIPS]
#define WS_CMAX  (2 * B_ROWS * NSTRIPS)                  // [B_ROWS][NCHUNK] chunk max (log2-scaled)
#define WS_M     (WS_CMAX + B_ROWS * NCHUNK)             // [B_ROWS] anchor max (NAT space)
#define WS_Z     (WS_M + B_ROWS)                         // [B_ROWS] softmax denom
#define WS_VLB   (WS_Z + B_ROWS)                         // [B_ROWS] certified winner lower bound
#define WS_CSTAR (WS_VLB + B_ROWS)                       // [B_ROWS] argmax chunk (int)
#define WS_BEST  (WS_CSTAR + B_ROWS)                     // [B_ROWS] u64 packed best
#define WS_ENORM (WS_BEST + 2 * B_ROWS)                  // [NCHUNK->2048] chunk max ||e||
#define WS_QNORM (WS_ENORM + 2048)                       // [B_ROWS] row ||q|| (unscaled)
#define WS_EHI   (WS_QNORM + B_ROWS)                     // bf16-hi table, pre-swizzled, NCHUNK*16KB
#define WS_ELO   (WS_EHI + NCHUNK * 4096)                // bf16-lo table
#define WS_END   (WS_ELO + NCHUNK * 4096)

typedef __attribute__((ext_vector_type(8))) unsigned short ushort8;
typedef __attribute__((ext_vector_type(8))) short short8;
typedef __attribute__((ext_vector_type(4))) float f32x4;

// ---------------- threefry2x32, key = (0, 42) = jax.random.key(42) ----------
// (bit-exact vs reference: verified absmax 0.0 in rounds 1-3)
__device__ __forceinline__ uint32_t rotl32(uint32_t x, int r) {
  return (x << r) | (x >> (32 - r));
}

__device__ __forceinline__ void threefry2x32_k42(uint32_t& x0, uint32_t& x1) {
  const uint32_t ks0 = 0u;
  const uint32_t ks1 = 42u;
  const uint32_t ks2 = 0x1BD11BDAu ^ 0u ^ 42u;
  x0 += ks0; x1 += ks1;
#define TF_R(r) { x0 += x1; x1 = rotl32(x1, (r)); x1 ^= x0; }
  TF_R(13) TF_R(15) TF_R(26) TF_R(6)
  x0 += ks1; x1 += ks2 + 1u;
  TF_R(17) TF_R(29) TF_R(16) TF_R(24)
  x0 += ks2; x1 += ks0 + 2u;
  TF_R(13) TF_R(15) TF_R(26) TF_R(6)
  x0 += ks0; x1 += ks1 + 3u;
  TF_R(17) TF_R(29) TF_R(16) TF_R(24)
  x0 += ks1; x1 += ks2 + 4u;
  TF_R(13) TF_R(15) TF_R(26) TF_R(6)
  x0 += ks2; x1 += ks0 + 5u;
#undef TF_R
}

__device__ __forceinline__ float gumbel_from_bits(uint32_t bits) {
  const uint32_t mant = bits >> 9;
  const float f = __uint_as_float(mant | 0x3f800000u) - 1.0f;  // exact
  const float l1 = mant ? log1pf(f - 1.0f) : -87.33654475055311f;  // ln(u)
  return -__logf(-l1);
}

__device__ __forceinline__ float gumbel_at(uint32_t flat_idx) {
  uint32_t x0 = 0u, x1 = flat_idx;
  threefry2x32_k42(x0, x1);
  return gumbel_from_bits(x0 ^ x1);
}

// order-preserving f32 pack with complemented index (first-occurrence argmax).
__device__ __forceinline__ unsigned long long pack_vn(float v, int n) {
  uint32_t u = __float_as_uint(v);
  u ^= ((uint32_t)((int32_t)u >> 31)) | 0x80000000u;
  return ((unsigned long long)u << 32) | (uint32_t)(0xFFFFFFFFu - (uint32_t)n);
}

__device__ __forceinline__ float unpack_v(unsigned long long p) {
  uint32_t u = (uint32_t)(p >> 32);
  u = (u & 0x80000000u) ? (u ^ 0x80000000u) : ~u;
  return __uint_as_float(u);
}

__device__ __forceinline__ int unpack_n(unsigned long long p) {
  return (int)(0xFFFFFFFFu - (uint32_t)(p & 0xFFFFFFFFull));
}

__device__ __forceinline__ unsigned long long umax64(unsigned long long a,
                                                     unsigned long long b) {
  return a > b ? a : b;
}

// Canonical f32 dot: all exact-path evaluations use THIS chain (consistent).
__device__ __forceinline__ float dot_q_e(const float4* q4, const float4* e4) {
  float s = 0.0f;
#pragma unroll
  for (int k4 = 0; k4 < 16; ++k4) {
    const float4 e = e4[k4];
    const float4 q = q4[k4];
    s = fmaf(q.x, e.x, s);
    s = fmaf(q.y, e.y, s);
    s = fmaf(q.z, e.z, s);
    s = fmaf(q.w, e.w, s);
  }
  return s;
}

// bf16 split helpers (explicit RNE)
__device__ __forceinline__ unsigned short f32_to_bf16_rne(float f) {
  const uint32_t u = __float_as_uint(f);
  return (unsigned short)((u + 0x7fffu + ((u >> 16) & 1u)) >> 16);
}
__device__ __forceinline__ float bf16_to_f32(unsigned short h) {
  return __uint_as_float(((uint32_t)h) << 16);
}

// ---------------- K0a: standalone per-chunk max ||e||_2 (fallback path) -----
__global__ __launch_bounds__(256) void advnet_enorm(const float* __restrict__ emb,
                                                    float* __restrict__ ws) {
  const int c = blockIdx.x;
  const int t = threadIdx.x;
  const int lane = t & 63;
  const int row = t >> 1;
  const int n = c * CHUNK + row;
  float ss = 0.0f;
  if (n < N_COLS) {
    const float4* p = (const float4*)emb + (size_t)n * 16 + (t & 1) * 8;
#pragma unroll
    for (int i = 0; i < 8; ++i) {
      const float4 v = p[i];
      ss = fmaf(v.x, v.x, ss); ss = fmaf(v.y, v.y, ss);
      ss = fmaf(v.z, v.z, ss); ss = fmaf(v.w, v.w, ss);
    }
  }
  ss += __shfl_xor(ss, 1, 64);
  float mx = ss;
  for (int off = 2; off < 64; off <<= 1) mx = fmaxf(mx, __shfl_xor(mx, off, 64));
  __shared__ float sm[4];
  if (lane == 0) sm[t >> 6] = mx;
  __syncthreads();
  if (t == 0)
    ws[WS_ENORM + c] =
        sqrtf(fmaxf(fmaxf(sm[0], sm[1]), fmaxf(sm[2], sm[3]))) * 1.00002f;
}

// ------- K0b: build pre-swizzled bf16 hi/lo tables + fused chunk ||e|| ------
// Table layout per chunk c: 1024 granules of 16B; granule L = row*8 + gz,
// gz = kq ^ (row&7). K1's linear global_load_lds reproduces the swizzled
// LDS layout its ds_reads expect.
__global__ __launch_bounds__(256) void advnet_ebuild(const float* __restrict__ emb,
                                                     float* __restrict__ ws) {
  const int c = blockIdx.x;
  const int t = threadIdx.x;
  char* hi_b = (char*)(ws + WS_EHI) + (size_t)c * 16384;
  char* lo_b = (char*)(ws + WS_ELO) + (size_t)c * 16384;
  float mx = 0.0f;
#pragma unroll
  for (int k = 0; k < 4; ++k) {
    const int j = t + 256 * k;          // source granule 0..1023
    const int row = j >> 3, kq = j & 7;
    const int n = c * CHUNK + row;
    ushort8 hi = (ushort8)0, lo = (ushort8)0;
    float ss = 0.0f;
    if (n < N_COLS) {
      const float4* ep = (const float4*)emb + (size_t)n * 16 + kq * 2;
      const float4 a0 = ep[0], a1 = ep[1];
      const float e[8] = {a0.x, a0.y, a0.z, a0.w, a1.x, a1.y, a1.z, a1.w};
#pragma unroll
      for (int j8 = 0; j8 < 8; ++j8) {
        const unsigned short h = f32_to_bf16_rne(e[j8]);
        hi[j8] = h;
        lo[j8] = f32_to_bf16_rne(e[j8] - bf16_to_f32(h));
        ss = fmaf(e[j8], e[j8], ss);
      }
    }
    const int gz = kq ^ (row & 7);
    *(ushort8*)(hi_b + (size_t)(row * 8 + gz) * 16) = hi;
    *(ushort8*)(lo_b + (size_t)(row * 8 + gz) * 16) = lo;
    // 8 consecutive lanes hold one row's 8 granules (8-aligned, within a wave)
    ss += __shfl_xor(ss, 1, 64);
    ss += __shfl_xor(ss, 2, 64);
    ss += __shfl_xor(ss, 4, 64);
    mx = fmaxf(mx, ss);
  }
  for (int off = 8; off < 64; off <<= 1) mx = fmaxf(mx, __shfl_xor(mx, off, 64));
  __shared__ float sm[4];
  if ((t & 63) == 0) sm[t >> 6] = mx;
  __syncthreads();
  if (t == 0)
    ws[WS_ENORM + c] =
        sqrtf(fmaxf(fmaxf(sm[0], sm[1]), fmaxf(sm[2], sm[3]))) * 1.00002f;
}

// ---- staging helpers for K1 ----
__device__ __forceinline__ void stage_tbl(const char* tb_hi, const char* tb_lo,
                                          unsigned short* eh, unsigned short* el,
                                          int c, int wave, int lane) {
  const size_t cb = (size_t)c * 16384 + (size_t)(wave * 1024 + lane * 16);
  const int wo = wave * 1024;
#pragma unroll
  for (int i = 0; i < 4; ++i) {
    const int off = i * 4096;
    __builtin_amdgcn_global_load_lds(
        (const __attribute__((address_space(1))) void*)(tb_hi + cb + off),
        (__attribute__((address_space(3))) void*)((char*)eh + wo + off), 16, 0, 0);
    __builtin_amdgcn_global_load_lds(
        (const __attribute__((address_space(1))) void*)(tb_lo + cb + off),
        (__attribute__((address_space(3))) void*)((char*)el + wo + off), 16, 0, 0);
  }
}

__device__ __forceinline__ void stage_conv(const float* __restrict__ emb,
                                           unsigned short* eh, unsigned short* el,
                                           int c, int tid) {
  const int n0 = c * CHUNK;
#pragma unroll
  for (int k = 0; k < 4; ++k) {
    const int p = tid + 256 * k;
    const int row = p >> 3, kq = p & 7;
    const int n = n0 + row;
    ushort8 hi = (ushort8)0, lo = (ushort8)0;
    if (n < N_COLS) {
      const float4* ep = (const float4*)emb + (size_t)n * 16 + kq * 2;
      const float4 a0 = ep[0], a1 = ep[1];
      const float e[8] = {a0.x, a0.y, a0.z, a0.w, a1.x, a1.y, a1.z, a1.w};
#pragma unroll
      for (int j = 0; j < 8; ++j) {
        const unsigned short h = f32_to_bf16_rne(e[j]);
        hi[j] = h;
        lo[j] = f32_to_bf16_rne(e[j] - bf16_to_f32(h));
      }
    }
    const int off = row * 64 + ((kq * 8) ^ ((row & 7) << 3));
    *(ushort8*)&eh[off] = hi;
    *(ushort8*)&el[off] = lo;
  }
}

// ------------------------- K1: MFMA GEMM pass -------------------------------
// 2048 blocks, 4 waves. Swizzled block mapping: raw = b8 + 8*(16a + rg),
// strip = 8a + b8 -> all 16 same-strip blocks (rg=0..15) share raw%8 (same
// XCD under round-robin) and are dispatch-adjacent => each 32KB table chunk
// is fetched into one XCD's L2 once and reused 16x (verified: FETCH 35MB, r7).
// SINGLE-buffer LDS (32KB) + 5 blocks/CU: stage latency (L2-hit) is hidden
// by cross-block TLP instead of in-block double buffering (r7 was 2 blocks/CU,
// occupancy-bound at 22%; throughput floor says ~40us fully overlapped).
// q pre-scaled by log2e so the epilogue uses raw exp2 (no mul, no mask).
template <bool TBL>
__global__ __launch_bounds__(256, 5) void advnet_gemm(
    const int* __restrict__ u_id, const int* __restrict__ pos_id,
    const float* __restrict__ emb, float* __restrict__ ws) {
  __shared__ unsigned short eh_s[8192], el_s[8192];

  const int tid = threadIdx.x;
  const int raw = blockIdx.x;
  const int b8 = raw & 7;
  const int rest = raw >> 3;
  const int rg = rest & 15;
  const int strip = b8 + 8 * (rest >> 4);
  const int wave = tid >> 6;
  const int lane = tid & 63;
  const int lc = lane & 15;
  const int lg = lane >> 4;

  // ---- stage q split (scaled by log2e) into eh/el, hoist frags to regs ----
#pragma unroll
  for (int k = 0; k < 4; ++k) {
    const int p = tid + 256 * k;
    const int row = p >> 3, kq = p & 7;
    const int b = rg * 128 + row;
    const float4* ua = (const float4*)emb + (size_t)u_id[b] * 16 + kq * 2;
    const float4* pa = (const float4*)emb + (size_t)pos_id[b] * 16 + kq * 2;
    const float4 a0 = ua[0], a1 = ua[1], c0 = pa[0], c1 = pa[1];
    const float q[8] = {(a0.x + c0.x) * LOG2E_F, (a0.y + c0.y) * LOG2E_F,
                        (a0.z + c0.z) * LOG2E_F, (a0.w + c0.w) * LOG2E_F,
                        (a1.x + c1.x) * LOG2E_F, (a1.y + c1.y) * LOG2E_F,
                        (a1.z + c1.z) * LOG2E_F, (a1.w + c1.w) * LOG2E_F};
    ushort8 hi, lo;
#pragma unroll
    for (int j = 0; j < 8; ++j) {
      const unsigned short h = f32_to_bf16_rne(q[j]);
      hi[j] = h;
      lo[j] = f32_to_bf16_rne(q[j] - bf16_to_f32(h));
    }
    const int off = row * 64 + ((kq * 8) ^ ((row & 7) << 3));
    *(ushort8*)&eh_s[off] = hi;
    *(ushort8*)&el_s[off] = lo;
  }
  __syncthreads();

  short8 qh_r[2][2], ql_r[2][2];  // [kh][rt]
#pragma unroll
  for (int kh = 0; kh < 2; ++kh)
#pragma unroll
    for (int rt = 0; rt < 2; ++rt) {
      const int r = wave * 32 + rt * 16 + lc;
      const int off = r * 64 + (((kh * 4 + lg) * 8) ^ ((r & 7) << 3));
      qh_r[kh][rt] = *(const short8*)&eh_s[off];
      ql_r[kh][rt] = *(const short8*)&el_s[off];
    }
  __syncthreads();  // frag reads done before e staging overwrites

  float m[8], Z[8];
#pragma unroll
  for (int s = 0; s < 8; ++s) { m[s] = NEG_HUGE; Z[s] = 0.0f; }

  const char* tb_hi = (const char*)(ws + WS_EHI);
  const char* tb_lo = (const char*)(ws + WS_ELO);

  for (int c = strip; c < NCHUNK; c += NSTRIPS) {
    if (TBL) stage_tbl(tb_hi, tb_lo, eh_s, el_s, c, wave, lane);
    else     stage_conv(emb, eh_s, el_s, c, tid);
    __syncthreads();  // drains global_load_lds + barrier

    // ---- MFMA: acc = qh*eh + qh*el + ql*eh over K=64 ----
    f32x4 acc[2][8];
#pragma unroll
    for (int rt = 0; rt < 2; ++rt)
#pragma unroll
      for (int ct = 0; ct < 8; ++ct) acc[rt][ct] = (f32x4){0.f, 0.f, 0.f, 0.f};

#pragma unroll
    for (int kh = 0; kh < 2; ++kh) {
#pragma unroll
      for (int ct = 0; ct < 8; ++ct) {
        const int col = ct * 16 + lc;
        const int off = col * 64 + (((kh * 4 + lg) * 8) ^ ((col & 7) << 3));
        const short8 ehf = *(const short8*)&eh_s[off];
        const short8 elf = *(const short8*)&el_s[off];
#pragma unroll
        for (int rt = 0; rt < 2; ++rt) {
          acc[rt][ct] = __builtin_amdgcn_mfma_f32_16x16x32_bf16(qh_r[kh][rt], ehf, acc[rt][ct], 0, 0, 0);
          acc[rt][ct] = __builtin_amdgcn_mfma_f32_16x16x32_bf16(qh_r[kh][rt], elf, acc[rt][ct], 0, 0, 0);
          acc[rt][ct] = __builtin_amdgcn_mfma_f32_16x16x32_bf16(ql_r[kh][rt], ehf, acc[rt][ct], 0, 0, 0);
        }
      }
    }

    // ---- epilogue (log2 space, no mask): online (m,Z) + chunk max ----
    // C layout (m89): col = lane&15, row = (lane>>4)*4 + reg.
#pragma unroll
    for (int rt = 0; rt < 2; ++rt) {
#pragma unroll
      for (int j = 0; j < 4; ++j) {
        const int s = rt * 4 + j;
        float cm = acc[rt][0][j];
#pragma unroll
        for (int ct = 1; ct < 8; ++ct) cm = fmaxf(cm, acc[rt][ct][j]);
        const float nm = fmaxf(m[s], cm);
        float za = 0.0f;
#pragma unroll
        for (int ct = 0; ct < 8; ++ct) za += EXP2F(acc[rt][ct][j] - nm);
        Z[s] = Z[s] * EXP2F(m[s] - nm) + za;
        m[s] = nm;
        float cr = cm;
        cr = fmaxf(cr, __shfl_xor(cr, 1, 64));
        cr = fmaxf(cr, __shfl_xor(cr, 2, 64));
        cr = fmaxf(cr, __shfl_xor(cr, 4, 64));
        cr = fmaxf(cr, __shfl_xor(cr, 8, 64));
        if (lc == 0) {
          const int row = rg * 128 + wave * 32 + rt * 16 + lg * 4 + j;
          ws[WS_CMAX + (size_t)row * NCHUNK + c] = cr;  // log2-scaled
        }
      }
    }
    __syncthreads();  // all LDS reads done before next stage overwrites
  }

  // ---- merge (m,Z) over the 16 lanes sharing each row; write partials ----
#pragma unroll
  for (int rt = 0; rt < 2; ++rt) {
#pragma unroll
    for (int j = 0; j < 4; ++j) {
      const int s = rt * 4 + j;
      float mi = m[s], Zi = Z[s];
      for (int off = 1; off < 16; off <<= 1) {
        const float om = __shfl_xor(mi, off, 64);
        const float oZ = __shfl_xor(Zi, off, 64);
        const float nm = fmaxf(mi, om);
        Zi = Zi * EXP2F(mi - nm) + oZ * EXP2F(om - nm);
        mi = nm;
      }
      if (lc == 0) {
        const int row = rg * 128 + wave * 32 + rt * 16 + lg * 4 + j;
        ws[WS_MPART + (size_t)row * NSTRIPS + strip] = mi;  // log2-scaled
        ws[WS_ZPART + (size_t)row * NSTRIPS + strip] = Zi;
      }
    }
  }
}

// ------- K2: per-row stats + seed winner from argmax chunk -> v_lb ----------
__global__ __launch_bounds__(128) void advnet_rowstat(
    const int* __restrict__ u_id, const int* __restrict__ pos_id,
    const float* __restrict__ emb, float* __restrict__ ws) {
  const int r = blockIdx.x;
  const int t = threadIdx.x;

  __shared__ float sA[2], sB[2];
  __shared__ unsigned long long sP[2];
  __shared__ float qrow[64];

  const size_t idx = (size_t)r * NSTRIPS + t;
  const float ms = ws[WS_MPART + idx];   // log2-scaled
  const float zs = ws[WS_ZPART + idx];
  float Ms = ms;
  for (int off = 1; off < 64; off <<= 1) Ms = fmaxf(Ms, __shfl_xor(Ms, off, 64));
  if ((t & 63) == 0) sA[t >> 6] = Ms;
  __syncthreads();
  Ms = fmaxf(sA[0], sA[1]);
  float z = zs * EXP2F(ms - Ms);
  for (int off = 1; off < 64; off <<= 1) z += __shfl_xor(z, off, 64);
  if ((t & 63) == 0) sB[t >> 6] = z;
  __syncthreads();
  const float Z = sB[0] + sB[1];
  const float M_nat = Ms * LN2_F;        // nat-space anchor

  // ---- c* = chunk containing the (scaled) row max ----
  unsigned long long cp = 0ull;
  for (int c = t; c < NCHUNK; c += 128)
    cp = umax64(cp, pack_vn(ws[WS_CMAX + (size_t)r * NCHUNK + c], c));
  for (int off = 1; off < 64; off <<= 1)
    cp = umax64(cp, __shfl_xor(cp, off, 64));
  if ((t & 63) == 0) sP[t >> 6] = cp;
  __syncthreads();
  cp = umax64(sP[0], sP[1]);
  const int cstar = unpack_n(cp);

  if (t < 16) {
    const float4 a = ((const float4*)emb)[(size_t)u_id[r] * 16 + t];
    const float4 c = ((const float4*)emb)[(size_t)pos_id[r] * 16 + t];
    ((float4*)qrow)[t] = make_float4(a.x + c.x, a.y + c.y, a.z + c.z, a.w + c.w);
  }
  __syncthreads();

  // ---- ||q|| (unscaled, upper-margined) ----
  {
    const float qv = qrow[t & 63];
    float ss = qv * qv;
    for (int off = 1; off < 64; off <<= 1) ss += __shfl_xor(ss, off, 64);
    if (t == 0) ws[WS_QNORM + r] = sqrtf(ss) * 1.00002f;
  }

  // ---- evaluate chunk c* under the HARD bound -> certified v_lb ----
  unsigned long long bp = 0ull;
  const int n = cstar * CHUNK + t;
  if (n < N_COLS) {
    const float s = dot_q_e((const float4*)qrow, (const float4*)emb + (size_t)n * 16);
    if (s != 0.0f && s >= M_nat - G_SPAN_HARD) {
      const uint32_t L = (uint32_t)r * (uint32_t)N_COLS + (uint32_t)n;
      bp = pack_vn(gumbel_at(L) + s, n);
    }
  }
  for (int off = 1; off < 64; off <<= 1)
    bp = umax64(bp, __shfl_xor(bp, off, 64));
  if ((t & 63) == 0) sP[t >> 6] = bp;
  __syncthreads();
  if (t == 0) {
    const unsigned long long best = umax64(sP[0], sP[1]);
    ((unsigned long long*)(ws + WS_BEST))[r] = best;   // seed (reset each call)
    ws[WS_VLB + r] = unpack_v(best);                   // certified lower bound (nat)
    ws[WS_M + r] = M_nat;
    ws[WS_Z + r] = Z;
    ((int*)ws)[WS_CSTAR + r] = cstar;
  }
}

// ---- K3: gumbel-first candidate scan. 2 blocks/row (parity-split chunks). --
// Column n can win only if g_n > v_lb - (cmax_nat_c + bb_c). Gumbels are pure
// VALU -> evaluate them FIRST; canonical f32 dots only for survivors.
#define SVCAP 2048
__global__ __launch_bounds__(256) void advnet_pick(
    const int* __restrict__ u_id, const int* __restrict__ pos_id,
    const float* __restrict__ emb, float* __restrict__ ws) {
  const int r = blockIdx.x >> 1;
  const int par = blockIdx.x & 1;
  const int t = threadIdx.x;

  __shared__ float qrow[64];
  __shared__ unsigned short cq[600];
  __shared__ float cqg[600];
  __shared__ unsigned int svpk[SVCAP];
  __shared__ float svg[SVCAP];
  __shared__ int cqn, svn;
  __shared__ unsigned long long sred[4];

  if (t == 0) { cqn = 0; svn = 0; }
  if (t < 16) {
    const float4 a = ((const float4*)emb)[(size_t)u_id[r] * 16 + t];
    const float4 c = ((const float4*)emb)[(size_t)pos_id[r] * 16 + t];
    ((float4*)qrow)[t] = make_float4(a.x + c.x, a.y + c.y, a.z + c.z, a.w + c.w);
  }
  const float vlb = ws[WS_VLB + r];
  const float bq = ws[WS_QNORM + r] * EPS_B;
  const int cstar = ((const int*)ws)[WS_CSTAR + r];
  __syncthreads();

  // ---- phase 1: candidate chunks of this parity -> LDS queue ----
  for (int c = par + 2 * t; c < NCHUNK; c += 512) {
    if (c == cstar) continue;  // fully covered by K2's seed
    const float cm = ws[WS_CMAX + (size_t)r * NCHUNK + c];  // log2-scaled
    const float gth = vlb - fmaf(cm, LN2_F, bq * ws[WS_ENORM + c]);
    if (gth < G_MAX_MARGIN) {
      const int k = atomicAdd(&cqn, 1);
      cq[k] = (unsigned short)c;   // max 586 per parity < 600
      cqg[k] = gth;
    }
  }
  __syncthreads();
  const int nq = cqn;
  const float4* qr4 = (const float4*)qrow;

  unsigned long long bp = 0ull;

  // ---- phase 2: 8 chunks/iter gumbel filter; drain survivors as needed ----
  for (int base = 0; base < nq; base += 8) {
    if (svn > SVCAP - 1024) {  // uniform decision (svn stable since last sync)
      __syncthreads();
      const int cnt = svn;
      for (int k = t; k < cnt; k += 256) {
        const int n = (int)svpk[k];
        const float s = dot_q_e(qr4, (const float4*)emb + (size_t)n * 16);
        if (s != 0.0f) bp = umax64(bp, pack_vn(svg[k] + s, n));
      }
      __syncthreads();
      if (t == 0) svn = 0;
      __syncthreads();
    }
#pragma unroll
    for (int u = 0; u < 4; ++u) {
      const int idx = t + 256 * u;
      const int slot = base + (idx >> 7);
      if (slot < nq) {
        const int n = (int)cq[slot] * CHUNK + (idx & 127);
        if (n < N_COLS) {
          const float g = gumbel_at((uint32_t)r * (uint32_t)N_COLS + (uint32_t)n);
          if (g > cqg[slot] - G_FILTER_SLACK) {
            const int k = atomicAdd(&svn, 1);
            if (k < SVCAP) { svpk[k] = (unsigned)n; svg[k] = g; }
          }
        }
      }
    }
    __syncthreads();  // pushes visible; svn settled for next-iter check
  }

  // ---- final drain ----
  {
    const int cnt = svn < SVCAP ? svn : SVCAP;
    for (int k = t; k < cnt; k += 256) {
      const int n = (int)svpk[k];
      const float s = dot_q_e(qr4, (const float4*)emb + (size_t)n * 16);
      if (s != 0.0f) bp = umax64(bp, pack_vn(svg[k] + s, n));
    }
  }

  // ---- block reduce + merge into per-row best ----
  for (int off = 1; off < 64; off <<= 1)
    bp = umax64(bp, __shfl_xor(bp, off, 64));
  if ((t & 63) == 0) sred[t >> 6] = bp;
  __syncthreads();
  if (t == 0) {
    const unsigned long long b =
        umax64(umax64(sred[0], sred[1]), umax64(sred[2], sred[3]));
    if (b) atomicMax((unsigned long long*)(ws + WS_BEST) + r, b);
  }
}

// --------------------------- K4: finalize outputs ---------------------------
__global__ __launch_bounds__(64) void advnet_final(
    const int* __restrict__ u_id, const int* __restrict__ pos_id,
    const float* __restrict__ emb, const float* __restrict__ ws,
    float* __restrict__ out) {
  const int r = blockIdx.x * 64 + threadIdx.x;
  if (r >= B_ROWS) return;
  const unsigned long long w = ((const unsigned long long*)(ws + WS_BEST))[r];
  const int n = unpack_n(w);
  const float4* qa = (const float4*)emb + (size_t)u_id[r] * 16;
  const float4* qb = (const float4*)emb + (size_t)pos_id[r] * 16;
  const float4* e4 = (const float4*)emb + (size_t)n * 16;
  float s = 0.0f;
#pragma unroll
  for (int k4 = 0; k4 < 16; ++k4) {
    const float4 a = qa[k4], b = qb[k4], e = e4[k4];
    float4 q;
    q.x = a.x + b.x; q.y = a.y + b.y; q.z = a.z + b.z; q.w = a.w + b.w;
    s = fmaf(q.x, e.x, s);
    s = fmaf(q.y, e.y, s);
    s = fmaf(q.z, e.z, s);
    s = fmaf(q.w, e.w, s);
  }
  out[r] = (float)n;
  out[B_ROWS + r] = __expf(s - ws[WS_M + r]) / ws[WS_Z + r];
}

extern "C" void kernel_launch(void* const* d_in, const int* in_sizes, int n_in,
                              void* d_out, int out_size, void* d_ws, size_t ws_size,
                              hipStream_t stream) {
  const int* u_id = (const int*)d_in[0];
  const int* pos_id = (const int*)d_in[1];
  // d_in[2] = train_mask: unused by the reference output
  const float* emb = (const float*)d_in[3];
  float* ws = (float*)d_ws;
  float* out = (float*)d_out;  // [2048 samples | 2048 probs], f32

  const size_t need = (size_t)WS_END * 4;  // ~47.9 MiB with tables
  const bool tbl = ws_size >= need;        // deterministic across calls

  if (tbl) {
    advnet_ebuild<<<dim3(NCHUNK), dim3(256), 0, stream>>>(emb, ws);  // fused enorm
    advnet_gemm<true><<<dim3(ROWG * NSTRIPS), dim3(256), 0, stream>>>(
        u_id, pos_id, emb, ws);
  } else {
    advnet_enorm<<<dim3(NCHUNK), dim3(256), 0, stream>>>(emb, ws);
    advnet_gemm<false><<<dim3(ROWG * NSTRIPS), dim3(256), 0, stream>>>(
        u_id, pos_id, emb, ws);
  }
  advnet_rowstat<<<dim3(B_ROWS), dim3(128), 0, stream>>>(u_id, pos_id, emb, ws);
  advnet_pick<<<dim3(B_ROWS * 2), dim3(256), 0, stream>>>(u_id, pos_id, emb, ws);
  advnet_final<<<dim3(B_ROWS / 64), dim3(64), 0, stream>>>(u_id, pos_id, emb, ws, out);
}

// Round 9
// 283.367 us; speedup vs baseline: 1.5653x; 1.5653x over previous
//
#include <hip/hip_runtime.h>
#include <stdint.h>

// Problem constants (from reference):
#define B_ROWS   2048
#define N_COLS   150000
#define NSTRIPS  128
#define CHUNK    128
#define NCHUNK   1172                             // ceil(150000/128), tail has 112 cols
#define ROWG     16                               // 2048/128 row groups

#define NEG_HUGE (-3.0e38f)
// Gumbel hard bounds: u in [tiny, 1-2^-23] -> g in [-4.46966, +15.94238].
#define G_SPAN_HARD  20.6f      // hard winner bound incl. mfma split slack
#define G_MAX_MARGIN 15.944f    // max achievable gumbel + logf-err margin
// Certified |s_canon - s_mfma_nat| <= ||q||2 * ||e||2 * EPS_B (invariant under
// the log2e pre-scaling: scaled-space error x ln2 == unscaled bound)
#define EPS_B        2.0e-4f
#define G_FILTER_SLACK 3e-5f    // f32 tie safety on the per-column gumbel filter

#define LOG2E_F 1.44269504088896340736f
#define LN2_F   0.69314718055994530942f

#if __has_builtin(__builtin_amdgcn_exp2f)
#define EXP2F(x) __builtin_amdgcn_exp2f(x)
#else
#define EXP2F(x) exp2f(x)
#endif

// ws layout (float offsets)
#define WS_MPART 0                                       // [B_ROWS][NSTRIPS] (log2-scaled)
#define WS_ZPART (B_ROWS * NSTRIPS)                      // [B_ROWS][NSTRIPS]
#define WS_CMAX  (2 * B_ROWS * NSTRIPS)                  // [B_ROWS][NCHUNK] chunk max (log2-scaled)
#define WS_M     (WS_CMAX + B_ROWS * NCHUNK)             // [B_ROWS] anchor max (NAT space)
#define WS_Z     (WS_M + B_ROWS)                         // [B_ROWS] softmax denom
#define WS_VLB   (WS_Z + B_ROWS)                         // [B_ROWS] certified winner lower bound
#define WS_CSTAR (WS_VLB + B_ROWS)                       // [B_ROWS] argmax chunk (int)
#define WS_BEST  (WS_CSTAR + B_ROWS)                     // [B_ROWS] u64 packed best
#define WS_ENORM (WS_BEST + 2 * B_ROWS)                  // [NCHUNK->2048] chunk max ||e||
#define WS_QNORM (WS_ENORM + 2048)                       // [B_ROWS] row ||q|| (unscaled)
#define WS_EHI   (WS_QNORM + B_ROWS)                     // bf16-hi table, pre-swizzled, NCHUNK*16KB
#define WS_ELO   (WS_EHI + NCHUNK * 4096)                // bf16-lo table
#define WS_END   (WS_ELO + NCHUNK * 4096)

typedef __attribute__((ext_vector_type(8))) unsigned short ushort8;
typedef __attribute__((ext_vector_type(8))) short short8;
typedef __attribute__((ext_vector_type(4))) float f32x4;

// ---------------- threefry2x32, key = (0, 42) = jax.random.key(42) ----------
// (bit-exact vs reference: verified absmax 0.0 in rounds 1-3)
__device__ __forceinline__ uint32_t rotl32(uint32_t x, int r) {
  return (x << r) | (x >> (32 - r));
}

__device__ __forceinline__ void threefry2x32_k42(uint32_t& x0, uint32_t& x1) {
  const uint32_t ks0 = 0u;
  const uint32_t ks1 = 42u;
  const uint32_t ks2 = 0x1BD11BDAu ^ 0u ^ 42u;
  x0 += ks0; x1 += ks1;
#define TF_R(r) { x0 += x1; x1 = rotl32(x1, (r)); x1 ^= x0; }
  TF_R(13) TF_R(15) TF_R(26) TF_R(6)
  x0 += ks1; x1 += ks2 + 1u;
  TF_R(17) TF_R(29) TF_R(16) TF_R(24)
  x0 += ks2; x1 += ks0 + 2u;
  TF_R(13) TF_R(15) TF_R(26) TF_R(6)
  x0 += ks0; x1 += ks1 + 3u;
  TF_R(17) TF_R(29) TF_R(16) TF_R(24)
  x0 += ks1; x1 += ks2 + 4u;
  TF_R(13) TF_R(15) TF_R(26) TF_R(6)
  x0 += ks2; x1 += ks0 + 5u;
#undef TF_R
}

__device__ __forceinline__ float gumbel_from_bits(uint32_t bits) {
  const uint32_t mant = bits >> 9;
  const float f = __uint_as_float(mant | 0x3f800000u) - 1.0f;  // exact
  const float l1 = mant ? log1pf(f - 1.0f) : -87.33654475055311f;  // ln(u)
  return -__logf(-l1);
}

__device__ __forceinline__ float gumbel_at(uint32_t flat_idx) {
  uint32_t x0 = 0u, x1 = flat_idx;
  threefry2x32_k42(x0, x1);
  return gumbel_from_bits(x0 ^ x1);
}

// order-preserving f32 pack with complemented index (first-occurrence argmax).
__device__ __forceinline__ unsigned long long pack_vn(float v, int n) {
  uint32_t u = __float_as_uint(v);
  u ^= ((uint32_t)((int32_t)u >> 31)) | 0x80000000u;
  return ((unsigned long long)u << 32) | (uint32_t)(0xFFFFFFFFu - (uint32_t)n);
}

__device__ __forceinline__ float unpack_v(unsigned long long p) {
  uint32_t u = (uint32_t)(p >> 32);
  u = (u & 0x80000000u) ? (u ^ 0x80000000u) : ~u;
  return __uint_as_float(u);
}

__device__ __forceinline__ int unpack_n(unsigned long long p) {
  return (int)(0xFFFFFFFFu - (uint32_t)(p & 0xFFFFFFFFull));
}

__device__ __forceinline__ unsigned long long umax64(unsigned long long a,
                                                     unsigned long long b) {
  return a > b ? a : b;
}

// Canonical f32 dot: all exact-path evaluations use THIS chain (consistent).
__device__ __forceinline__ float dot_q_e(const float4* q4, const float4* e4) {
  float s = 0.0f;
#pragma unroll
  for (int k4 = 0; k4 < 16; ++k4) {
    const float4 e = e4[k4];
    const float4 q = q4[k4];
    s = fmaf(q.x, e.x, s);
    s = fmaf(q.y, e.y, s);
    s = fmaf(q.z, e.z, s);
    s = fmaf(q.w, e.w, s);
  }
  return s;
}

// bf16 split helpers (explicit RNE)
__device__ __forceinline__ unsigned short f32_to_bf16_rne(float f) {
  const uint32_t u = __float_as_uint(f);
  return (unsigned short)((u + 0x7fffu + ((u >> 16) & 1u)) >> 16);
}
__device__ __forceinline__ float bf16_to_f32(unsigned short h) {
  return __uint_as_float(((uint32_t)h) << 16);
}

// ---------------- K0a: standalone per-chunk max ||e||_2 (fallback path) -----
__global__ __launch_bounds__(256) void advnet_enorm(const float* __restrict__ emb,
                                                    float* __restrict__ ws) {
  const int c = blockIdx.x;
  const int t = threadIdx.x;
  const int lane = t & 63;
  const int row = t >> 1;
  const int n = c * CHUNK + row;
  float ss = 0.0f;
  if (n < N_COLS) {
    const float4* p = (const float4*)emb + (size_t)n * 16 + (t & 1) * 8;
#pragma unroll
    for (int i = 0; i < 8; ++i) {
      const float4 v = p[i];
      ss = fmaf(v.x, v.x, ss); ss = fmaf(v.y, v.y, ss);
      ss = fmaf(v.z, v.z, ss); ss = fmaf(v.w, v.w, ss);
    }
  }
  ss += __shfl_xor(ss, 1, 64);
  float mx = ss;
  for (int off = 2; off < 64; off <<= 1) mx = fmaxf(mx, __shfl_xor(mx, off, 64));
  __shared__ float sm[4];
  if (lane == 0) sm[t >> 6] = mx;
  __syncthreads();
  if (t == 0)
    ws[WS_ENORM + c] =
        sqrtf(fmaxf(fmaxf(sm[0], sm[1]), fmaxf(sm[2], sm[3]))) * 1.00002f;
}

// ------- K0b: build pre-swizzled bf16 hi/lo tables + fused chunk ||e|| ------
// Table layout per chunk c: 1024 granules of 16B; granule L = row*8 + gz,
// gz = kq ^ (row&7). K1's linear global_load_lds reproduces the swizzled
// LDS layout its ds_reads expect.
__global__ __launch_bounds__(256) void advnet_ebuild(const float* __restrict__ emb,
                                                     float* __restrict__ ws) {
  const int c = blockIdx.x;
  const int t = threadIdx.x;
  char* hi_b = (char*)(ws + WS_EHI) + (size_t)c * 16384;
  char* lo_b = (char*)(ws + WS_ELO) + (size_t)c * 16384;
  float mx = 0.0f;
#pragma unroll
  for (int k = 0; k < 4; ++k) {
    const int j = t + 256 * k;          // source granule 0..1023
    const int row = j >> 3, kq = j & 7;
    const int n = c * CHUNK + row;
    ushort8 hi = (ushort8)0, lo = (ushort8)0;
    float ss = 0.0f;
    if (n < N_COLS) {
      const float4* ep = (const float4*)emb + (size_t)n * 16 + kq * 2;
      const float4 a0 = ep[0], a1 = ep[1];
      const float e[8] = {a0.x, a0.y, a0.z, a0.w, a1.x, a1.y, a1.z, a1.w};
#pragma unroll
      for (int j8 = 0; j8 < 8; ++j8) {
        const unsigned short h = f32_to_bf16_rne(e[j8]);
        hi[j8] = h;
        lo[j8] = f32_to_bf16_rne(e[j8] - bf16_to_f32(h));
        ss = fmaf(e[j8], e[j8], ss);
      }
    }
    const int gz = kq ^ (row & 7);
    *(ushort8*)(hi_b + (size_t)(row * 8 + gz) * 16) = hi;
    *(ushort8*)(lo_b + (size_t)(row * 8 + gz) * 16) = lo;
    // 8 consecutive lanes hold one row's 8 granules (8-aligned, within a wave)
    ss += __shfl_xor(ss, 1, 64);
    ss += __shfl_xor(ss, 2, 64);
    ss += __shfl_xor(ss, 4, 64);
    mx = fmaxf(mx, ss);
  }
  for (int off = 8; off < 64; off <<= 1) mx = fmaxf(mx, __shfl_xor(mx, off, 64));
  __shared__ float sm[4];
  if ((t & 63) == 0) sm[t >> 6] = mx;
  __syncthreads();
  if (t == 0)
    ws[WS_ENORM + c] =
        sqrtf(fmaxf(fmaxf(sm[0], sm[1]), fmaxf(sm[2], sm[3]))) * 1.00002f;
}

// ---- staging helpers for K1 ----
__device__ __forceinline__ void stage_tbl(const char* tb_hi, const char* tb_lo,
                                          unsigned short* eh, unsigned short* el,
                                          int c, int wave, int lane) {
  const size_t cb = (size_t)c * 16384 + (size_t)(wave * 1024 + lane * 16);
  const int wo = wave * 1024;
#pragma unroll
  for (int i = 0; i < 4; ++i) {
    const int off = i * 4096;
    __builtin_amdgcn_global_load_lds(
        (const __attribute__((address_space(1))) void*)(tb_hi + cb + off),
        (__attribute__((address_space(3))) void*)((char*)eh + wo + off), 16, 0, 0);
    __builtin_amdgcn_global_load_lds(
        (const __attribute__((address_space(1))) void*)(tb_lo + cb + off),
        (__attribute__((address_space(3))) void*)((char*)el + wo + off), 16, 0, 0);
  }
}

__device__ __forceinline__ void stage_conv(const float* __restrict__ emb,
                                           unsigned short* eh, unsigned short* el,
                                           int c, int tid) {
  const int n0 = c * CHUNK;
#pragma unroll
  for (int k = 0; k < 4; ++k) {
    const int p = tid + 256 * k;
    const int row = p >> 3, kq = p & 7;
    const int n = n0 + row;
    ushort8 hi = (ushort8)0, lo = (ushort8)0;
    if (n < N_COLS) {
      const float4* ep = (const float4*)emb + (size_t)n * 16 + kq * 2;
      const float4 a0 = ep[0], a1 = ep[1];
      const float e[8] = {a0.x, a0.y, a0.z, a0.w, a1.x, a1.y, a1.z, a1.w};
#pragma unroll
      for (int j = 0; j < 8; ++j) {
        const unsigned short h = f32_to_bf16_rne(e[j]);
        hi[j] = h;
        lo[j] = f32_to_bf16_rne(e[j] - bf16_to_f32(h));
      }
    }
    const int off = row * 64 + ((kq * 8) ^ ((row & 7) << 3));
    *(ushort8*)&eh[off] = hi;
    *(ushort8*)&el[off] = lo;
  }
}

// ------------------------- K1: MFMA GEMM pass -------------------------------
// 2048 blocks, 4 waves. Swizzled block mapping: raw = b8 + 8*(16a + rg),
// strip = 8a + b8 -> all 16 same-strip blocks (rg=0..15) share raw%8 (same
// XCD under round-robin) and are dispatch-adjacent => each 32KB table chunk
// is fetched into one XCD's L2 once and reused 16x (verified: FETCH 35MB, r7).
// Single-buffer LDS (32KB); __launch_bounds__(256,4): 128-VGPR cap covers the
// ~88-reg working set WITHOUT spill (r8's (256,5)=102-cap spilled: VGPR 48,
// 662MB scratch writes). 4 blocks/CU = 16 waves/CU hides stage latency by TLP.
// q pre-scaled by log2e so the epilogue uses raw exp2 (no mul, no mask).
template <bool TBL>
__global__ __launch_bounds__(256, 4) void advnet_gemm(
    const int* __restrict__ u_id, const int* __restrict__ pos_id,
    const float* __restrict__ emb, float* __restrict__ ws) {
  __shared__ unsigned short eh_s[8192], el_s[8192];

  const int tid = threadIdx.x;
  const int raw = blockIdx.x;
  const int b8 = raw & 7;
  const int rest = raw >> 3;
  const int rg = rest & 15;
  const int strip = b8 + 8 * (rest >> 4);
  const int wave = tid >> 6;
  const int lane = tid & 63;
  const int lc = lane & 15;
  const int lg = lane >> 4;

  // ---- stage q split (scaled by log2e) into eh/el, hoist frags to regs ----
#pragma unroll
  for (int k = 0; k < 4; ++k) {
    const int p = tid + 256 * k;
    const int row = p >> 3, kq = p & 7;
    const int b = rg * 128 + row;
    const float4* ua = (const float4*)emb + (size_t)u_id[b] * 16 + kq * 2;
    const float4* pa = (const float4*)emb + (size_t)pos_id[b] * 16 + kq * 2;
    const float4 a0 = ua[0], a1 = ua[1], c0 = pa[0], c1 = pa[1];
    const float q[8] = {(a0.x + c0.x) * LOG2E_F, (a0.y + c0.y) * LOG2E_F,
                        (a0.z + c0.z) * LOG2E_F, (a0.w + c0.w) * LOG2E_F,
                        (a1.x + c1.x) * LOG2E_F, (a1.y + c1.y) * LOG2E_F,
                        (a1.z + c1.z) * LOG2E_F, (a1.w + c1.w) * LOG2E_F};
    ushort8 hi, lo;
#pragma unroll
    for (int j = 0; j < 8; ++j) {
      const unsigned short h = f32_to_bf16_rne(q[j]);
      hi[j] = h;
      lo[j] = f32_to_bf16_rne(q[j] - bf16_to_f32(h));
    }
    const int off = row * 64 + ((kq * 8) ^ ((row & 7) << 3));
    *(ushort8*)&eh_s[off] = hi;
    *(ushort8*)&el_s[off] = lo;
  }
  __syncthreads();

  short8 qh_r[2][2], ql_r[2][2];  // [kh][rt]
#pragma unroll
  for (int kh = 0; kh < 2; ++kh)
#pragma unroll
    for (int rt = 0; rt < 2; ++rt) {
      const int r = wave * 32 + rt * 16 + lc;
      const int off = r * 64 + (((kh * 4 + lg) * 8) ^ ((r & 7) << 3));
      qh_r[kh][rt] = *(const short8*)&eh_s[off];
      ql_r[kh][rt] = *(const short8*)&el_s[off];
    }
  __syncthreads();  // frag reads done before e staging overwrites

  float m[8], Z[8];
#pragma unroll
  for (int s = 0; s < 8; ++s) { m[s] = NEG_HUGE; Z[s] = 0.0f; }

  const char* tb_hi = (const char*)(ws + WS_EHI);
  const char* tb_lo = (const char*)(ws + WS_ELO);

  for (int c = strip; c < NCHUNK; c += NSTRIPS) {
    if (TBL) stage_tbl(tb_hi, tb_lo, eh_s, el_s, c, wave, lane);
    else     stage_conv(emb, eh_s, el_s, c, tid);
    __syncthreads();  // drains global_load_lds + barrier

    // ---- MFMA: acc = qh*eh + qh*el + ql*eh over K=64 ----
    f32x4 acc[2][8];
#pragma unroll
    for (int rt = 0; rt < 2; ++rt)
#pragma unroll
      for (int ct = 0; ct < 8; ++ct) acc[rt][ct] = (f32x4){0.f, 0.f, 0.f, 0.f};

#pragma unroll
    for (int kh = 0; kh < 2; ++kh) {
#pragma unroll
      for (int ct = 0; ct < 8; ++ct) {
        const int col = ct * 16 + lc;
        const int off = col * 64 + (((kh * 4 + lg) * 8) ^ ((col & 7) << 3));
        const short8 ehf = *(const short8*)&eh_s[off];
        const short8 elf = *(const short8*)&el_s[off];
#pragma unroll
        for (int rt = 0; rt < 2; ++rt) {
          acc[rt][ct] = __builtin_amdgcn_mfma_f32_16x16x32_bf16(qh_r[kh][rt], ehf, acc[rt][ct], 0, 0, 0);
          acc[rt][ct] = __builtin_amdgcn_mfma_f32_16x16x32_bf16(qh_r[kh][rt], elf, acc[rt][ct], 0, 0, 0);
          acc[rt][ct] = __builtin_amdgcn_mfma_f32_16x16x32_bf16(ql_r[kh][rt], ehf, acc[rt][ct], 0, 0, 0);
        }
      }
    }

    // ---- epilogue (log2 space, no mask): online (m,Z) + chunk max ----
    // C layout (m89): col = lane&15, row = (lane>>4)*4 + reg.
#pragma unroll
    for (int rt = 0; rt < 2; ++rt) {
#pragma unroll
      for (int j = 0; j < 4; ++j) {
        const int s = rt * 4 + j;
        float cm = acc[rt][0][j];
#pragma unroll
        for (int ct = 1; ct < 8; ++ct) cm = fmaxf(cm, acc[rt][ct][j]);
        const float nm = fmaxf(m[s], cm);
        float za = 0.0f;
#pragma unroll
        for (int ct = 0; ct < 8; ++ct) za += EXP2F(acc[rt][ct][j] - nm);
        Z[s] = Z[s] * EXP2F(m[s] - nm) + za;
        m[s] = nm;
        float cr = cm;
        cr = fmaxf(cr, __shfl_xor(cr, 1, 64));
        cr = fmaxf(cr, __shfl_xor(cr, 2, 64));
        cr = fmaxf(cr, __shfl_xor(cr, 4, 64));
        cr = fmaxf(cr, __shfl_xor(cr, 8, 64));
        if (lc == 0) {
          const int row = rg * 128 + wave * 32 + rt * 16 + lg * 4 + j;
          ws[WS_CMAX + (size_t)row * NCHUNK + c] = cr;  // log2-scaled
        }
      }
    }
    __syncthreads();  // all LDS reads done before next stage overwrites
  }

  // ---- merge (m,Z) over the 16 lanes sharing each row; write partials ----
#pragma unroll
  for (int rt = 0; rt < 2; ++rt) {
#pragma unroll
    for (int j = 0; j < 4; ++j) {
      const int s = rt * 4 + j;
      float mi = m[s], Zi = Z[s];
      for (int off = 1; off < 16; off <<= 1) {
        const float om = __shfl_xor(mi, off, 64);
        const float oZ = __shfl_xor(Zi, off, 64);
        const float nm = fmaxf(mi, om);
        Zi = Zi * EXP2F(mi - nm) + oZ * EXP2F(om - nm);
        mi = nm;
      }
      if (lc == 0) {
        const int row = rg * 128 + wave * 32 + rt * 16 + lg * 4 + j;
        ws[WS_MPART + (size_t)row * NSTRIPS + strip] = mi;  // log2-scaled
        ws[WS_ZPART + (size_t)row * NSTRIPS + strip] = Zi;
      }
    }
  }
}

// ------- K2: per-row stats + seed winner from argmax chunk -> v_lb ----------
__global__ __launch_bounds__(128) void advnet_rowstat(
    const int* __restrict__ u_id, const int* __restrict__ pos_id,
    const float* __restrict__ emb, float* __restrict__ ws) {
  const int r = blockIdx.x;
  const int t = threadIdx.x;

  __shared__ float sA[2], sB[2];
  __shared__ unsigned long long sP[2];
  __shared__ float qrow[64];

  const size_t idx = (size_t)r * NSTRIPS + t;
  const float ms = ws[WS_MPART + idx];   // log2-scaled
  const float zs = ws[WS_ZPART + idx];
  float Ms = ms;
  for (int off = 1; off < 64; off <<= 1) Ms = fmaxf(Ms, __shfl_xor(Ms, off, 64));
  if ((t & 63) == 0) sA[t >> 6] = Ms;
  __syncthreads();
  Ms = fmaxf(sA[0], sA[1]);
  float z = zs * EXP2F(ms - Ms);
  for (int off = 1; off < 64; off <<= 1) z += __shfl_xor(z, off, 64);
  if ((t & 63) == 0) sB[t >> 6] = z;
  __syncthreads();
  const float Z = sB[0] + sB[1];
  const float M_nat = Ms * LN2_F;        // nat-space anchor

  // ---- c* = chunk containing the (scaled) row max ----
  unsigned long long cp = 0ull;
  for (int c = t; c < NCHUNK; c += 128)
    cp = umax64(cp, pack_vn(ws[WS_CMAX + (size_t)r * NCHUNK + c], c));
  for (int off = 1; off < 64; off <<= 1)
    cp = umax64(cp, __shfl_xor(cp, off, 64));
  if ((t & 63) == 0) sP[t >> 6] = cp;
  __syncthreads();
  cp = umax64(sP[0], sP[1]);
  const int cstar = unpack_n(cp);

  if (t < 16) {
    const float4 a = ((const float4*)emb)[(size_t)u_id[r] * 16 + t];
    const float4 c = ((const float4*)emb)[(size_t)pos_id[r] * 16 + t];
    ((float4*)qrow)[t] = make_float4(a.x + c.x, a.y + c.y, a.z + c.z, a.w + c.w);
  }
  __syncthreads();

  // ---- ||q|| (unscaled, upper-margined) ----
  {
    const float qv = qrow[t & 63];
    float ss = qv * qv;
    for (int off = 1; off < 64; off <<= 1) ss += __shfl_xor(ss, off, 64);
    if (t == 0) ws[WS_QNORM + r] = sqrtf(ss) * 1.00002f;
  }

  // ---- evaluate chunk c* under the HARD bound -> certified v_lb ----
  unsigned long long bp = 0ull;
  const int n = cstar * CHUNK + t;
  if (n < N_COLS) {
    const float s = dot_q_e((const float4*)qrow, (const float4*)emb + (size_t)n * 16);
    if (s != 0.0f && s >= M_nat - G_SPAN_HARD) {
      const uint32_t L = (uint32_t)r * (uint32_t)N_COLS + (uint32_t)n;
      bp = pack_vn(gumbel_at(L) + s, n);
    }
  }
  for (int off = 1; off < 64; off <<= 1)
    bp = umax64(bp, __shfl_xor(bp, off, 64));
  if ((t & 63) == 0) sP[t >> 6] = bp;
  __syncthreads();
  if (t == 0) {
    const unsigned long long best = umax64(sP[0], sP[1]);
    ((unsigned long long*)(ws + WS_BEST))[r] = best;   // seed (reset each call)
    ws[WS_VLB + r] = unpack_v(best);                   // certified lower bound (nat)
    ws[WS_M + r] = M_nat;
    ws[WS_Z + r] = Z;
    ((int*)ws)[WS_CSTAR + r] = cstar;
  }
}

// ---- K3: gumbel-first candidate scan. 2 blocks/row (parity-split chunks). --
// Column n can win only if g_n > v_lb - (cmax_nat_c + bb_c). Gumbels are pure
// VALU -> evaluate them FIRST; canonical f32 dots only for survivors.
#define SVCAP 2048
__global__ __launch_bounds__(256) void advnet_pick(
    const int* __restrict__ u_id, const int* __restrict__ pos_id,
    const float* __restrict__ emb, float* __restrict__ ws) {
  const int r = blockIdx.x >> 1;
  const int par = blockIdx.x & 1;
  const int t = threadIdx.x;

  __shared__ float qrow[64];
  __shared__ unsigned short cq[600];
  __shared__ float cqg[600];
  __shared__ unsigned int svpk[SVCAP];
  __shared__ float svg[SVCAP];
  __shared__ int cqn, svn;
  __shared__ unsigned long long sred[4];

  if (t == 0) { cqn = 0; svn = 0; }
  if (t < 16) {
    const float4 a = ((const float4*)emb)[(size_t)u_id[r] * 16 + t];
    const float4 c = ((const float4*)emb)[(size_t)pos_id[r] * 16 + t];
    ((float4*)qrow)[t] = make_float4(a.x + c.x, a.y + c.y, a.z + c.z, a.w + c.w);
  }
  const float vlb = ws[WS_VLB + r];
  const float bq = ws[WS_QNORM + r] * EPS_B;
  const int cstar = ((const int*)ws)[WS_CSTAR + r];
  __syncthreads();

  // ---- phase 1: candidate chunks of this parity -> LDS queue ----
  for (int c = par + 2 * t; c < NCHUNK; c += 512) {
    if (c == cstar) continue;  // fully covered by K2's seed
    const float cm = ws[WS_CMAX + (size_t)r * NCHUNK + c];  // log2-scaled
    const float gth = vlb - fmaf(cm, LN2_F, bq * ws[WS_ENORM + c]);
    if (gth < G_MAX_MARGIN) {
      const int k = atomicAdd(&cqn, 1);
      cq[k] = (unsigned short)c;   // max 586 per parity < 600
      cqg[k] = gth;
    }
  }
  __syncthreads();
  const int nq = cqn;
  const float4* qr4 = (const float4*)qrow;

  unsigned long long bp = 0ull;

  // ---- phase 2: 8 chunks/iter gumbel filter; drain survivors as needed ----
  for (int base = 0; base < nq; base += 8) {
    if (svn > SVCAP - 1024) {  // uniform decision (svn stable since last sync)
      __syncthreads();
      const int cnt = svn;
      for (int k = t; k < cnt; k += 256) {
        const int n = (int)svpk[k];
        const float s = dot_q_e(qr4, (const float4*)emb + (size_t)n * 16);
        if (s != 0.0f) bp = umax64(bp, pack_vn(svg[k] + s, n));
      }
      __syncthreads();
      if (t == 0) svn = 0;
      __syncthreads();
    }
#pragma unroll
    for (int u = 0; u < 4; ++u) {
      const int idx = t + 256 * u;
      const int slot = base + (idx >> 7);
      if (slot < nq) {
        const int n = (int)cq[slot] * CHUNK + (idx & 127);
        if (n < N_COLS) {
          const float g = gumbel_at((uint32_t)r * (uint32_t)N_COLS + (uint32_t)n);
          if (g > cqg[slot] - G_FILTER_SLACK) {
            const int k = atomicAdd(&svn, 1);
            if (k < SVCAP) { svpk[k] = (unsigned)n; svg[k] = g; }
          }
        }
      }
    }
    __syncthreads();  // pushes visible; svn settled for next-iter check
  }

  // ---- final drain ----
  {
    const int cnt = svn < SVCAP ? svn : SVCAP;
    for (int k = t; k < cnt; k += 256) {
      const int n = (int)svpk[k];
      const float s = dot_q_e(qr4, (const float4*)emb + (size_t)n * 16);
      if (s != 0.0f) bp = umax64(bp, pack_vn(svg[k] + s, n));
    }
  }

  // ---- block reduce + merge into per-row best ----
  for (int off = 1; off < 64; off <<= 1)
    bp = umax64(bp, __shfl_xor(bp, off, 64));
  if ((t & 63) == 0) sred[t >> 6] = bp;
  __syncthreads();
  if (t == 0) {
    const unsigned long long b =
        umax64(umax64(sred[0], sred[1]), umax64(sred[2], sred[3]));
    if (b) atomicMax((unsigned long long*)(ws + WS_BEST) + r, b);
  }
}

// --------------------------- K4: finalize outputs ---------------------------
__global__ __launch_bounds__(64) void advnet_final(
    const int* __restrict__ u_id, const int* __restrict__ pos_id,
    const float* __restrict__ emb, const float* __restrict__ ws,
    float* __restrict__ out) {
  const int r = blockIdx.x * 64 + threadIdx.x;
  if (r >= B_ROWS) return;
  const unsigned long long w = ((const unsigned long long*)(ws + WS_BEST))[r];
  const int n = unpack_n(w);
  const float4* qa = (const float4*)emb + (size_t)u_id[r] * 16;
  const float4* qb = (const float4*)emb + (size_t)pos_id[r] * 16;
  const float4* e4 = (const float4*)emb + (size_t)n * 16;
  float s = 0.0f;
#pragma unroll
  for (int k4 = 0; k4 < 16; ++k4) {
    const float4 a = qa[k4], b = qb[k4], e = e4[k4];
    float4 q;
    q.x = a.x + b.x; q.y = a.y + b.y; q.z = a.z + b.z; q.w = a.w + b.w;
    s = fmaf(q.x, e.x, s);
    s = fmaf(q.y, e.y, s);
    s = fmaf(q.z, e.z, s);
    s = fmaf(q.w, e.w, s);
  }
  out[r] = (float)n;
  out[B_ROWS + r] = __expf(s - ws[WS_M + r]) / ws[WS_Z + r];
}

extern "C" void kernel_launch(void* const* d_in, const int* in_sizes, int n_in,
                              void* d_out, int out_size, void* d_ws, size_t ws_size,
                              hipStream_t stream) {
  const int* u_id = (const int*)d_in[0];
  const int* pos_id = (const int*)d_in[1];
  // d_in[2] = train_mask: unused by the reference output
  const float* emb = (const float*)d_in[3];
  float* ws = (float*)d_ws;
  float* out = (float*)d_out;  // [2048 samples | 2048 probs], f32

  const size_t need = (size_t)WS_END * 4;  // ~47.9 MiB with tables
  const bool tbl = ws_size >= need;        // deterministic across calls

  if (tbl) {
    advnet_ebuild<<<dim3(NCHUNK), dim3(256), 0, stream>>>(emb, ws);  // fused enorm
    advnet_gemm<true><<<dim3(ROWG * NSTRIPS), dim3(256), 0, stream>>>(
        u_id, pos_id, emb, ws);
  } else {
    advnet_enorm<<<dim3(NCHUNK), dim3(256), 0, stream>>>(emb, ws);
    advnet_gemm<false><<<dim3(ROWG * NSTRIPS), dim3(256), 0, stream>>>(
        u_id, pos_id, emb, ws);
  }
  advnet_rowstat<<<dim3(B_ROWS), dim3(128), 0, stream>>>(u_id, pos_id, emb, ws);
  advnet_pick<<<dim3(B_ROWS * 2), dim3(256), 0, stream>>>(u_id, pos_id, emb, ws);
  advnet_final<<<dim3(B_ROWS / 64), dim3(64), 0, stream>>>(u_id, pos_id, emb, ws, out);
}

// Round 10
// 258.564 us; speedup vs baseline: 1.7155x; 1.0959x over previous
//
#include <hip/hip_runtime.h>
#include <stdint.h>

// Problem constants (from reference):
#define B_ROWS   2048
#define N_COLS   150000
#define NSTRIPS  128
#define CHUNK    128
#define NCHUNK   1172                             // ceil(150000/128), tail has 112 cols
#define ROWG     16                               // 2048/128 row groups

#define NEG_HUGE (-3.0e38f)
// Gumbel hard bounds: u in [tiny, 1-2^-23] -> g in [-4.46966, +15.94238].
#define G_SPAN_HARD  20.6f      // hard winner bound incl. mfma split slack
#define G_MAX_MARGIN 15.944f    // max achievable gumbel + logf-err margin
// Certified |s_canon - s_mfma_nat| <= ||q||2 * ||e||2 * EPS_B (invariant under
// the log2e pre-scaling: scaled-space error x ln2 == unscaled bound)
#define EPS_B        2.0e-4f
#define G_FILTER_SLACK 3e-5f    // f32 tie safety on the per-column gumbel filter

#define LOG2E_F 1.44269504088896340736f
#define LN2_F   0.69314718055994530942f

#if __has_builtin(__builtin_amdgcn_exp2f)
#define EXP2F(x) __builtin_amdgcn_exp2f(x)
#else
#define EXP2F(x) exp2f(x)
#endif

// ws layout (float offsets)
#define WS_MPART 0                                       // [B_ROWS][NSTRIPS] (log2-scaled)
#define WS_ZPART (B_ROWS * NSTRIPS)                      // [B_ROWS][NSTRIPS]
#define WS_CMAX  (2 * B_ROWS * NSTRIPS)                  // [B_ROWS][NCHUNK] chunk max (log2-scaled)
#define WS_M     (WS_CMAX + B_ROWS * NCHUNK)             // [B_ROWS] anchor max (NAT space)
#define WS_Z     (WS_M + B_ROWS)                         // [B_ROWS] softmax denom
#define WS_VLB   (WS_Z + B_ROWS)                         // [B_ROWS] certified winner lower bound
#define WS_CSTAR (WS_VLB + B_ROWS)                       // [B_ROWS] argmax chunk (int)
#define WS_BEST  (WS_CSTAR + B_ROWS)                     // [B_ROWS] u64 packed best
#define WS_ENORM (WS_BEST + 2 * B_ROWS)                  // [NCHUNK->2048] chunk max ||e||
#define WS_QNORM (WS_ENORM + 2048)                       // [B_ROWS] row ||q|| (unscaled)
#define WS_EHI   (WS_QNORM + B_ROWS)                     // bf16-hi table, pre-swizzled, NCHUNK*16KB
#define WS_ELO   (WS_EHI + NCHUNK * 4096)                // bf16-lo table
#define WS_END   (WS_ELO + NCHUNK * 4096)

typedef __attribute__((ext_vector_type(8))) unsigned short ushort8;
typedef __attribute__((ext_vector_type(8))) short short8;
typedef __attribute__((ext_vector_type(4))) float f32x4;

// ---------------- threefry2x32, key = (0, 42) = jax.random.key(42) ----------
// (bit-exact vs reference: verified absmax 0.0 in rounds 1-3)
__device__ __forceinline__ uint32_t rotl32(uint32_t x, int r) {
  return (x << r) | (x >> (32 - r));
}

__device__ __forceinline__ void threefry2x32_k42(uint32_t& x0, uint32_t& x1) {
  const uint32_t ks0 = 0u;
  const uint32_t ks1 = 42u;
  const uint32_t ks2 = 0x1BD11BDAu ^ 0u ^ 42u;
  x0 += ks0; x1 += ks1;
#define TF_R(r) { x0 += x1; x1 = rotl32(x1, (r)); x1 ^= x0; }
  TF_R(13) TF_R(15) TF_R(26) TF_R(6)
  x0 += ks1; x1 += ks2 + 1u;
  TF_R(17) TF_R(29) TF_R(16) TF_R(24)
  x0 += ks2; x1 += ks0 + 2u;
  TF_R(13) TF_R(15) TF_R(26) TF_R(6)
  x0 += ks0; x1 += ks1 + 3u;
  TF_R(17) TF_R(29) TF_R(16) TF_R(24)
  x0 += ks1; x1 += ks2 + 4u;
  TF_R(13) TF_R(15) TF_R(26) TF_R(6)
  x0 += ks2; x1 += ks0 + 5u;
#undef TF_R
}

__device__ __forceinline__ float gumbel_from_bits(uint32_t bits) {
  const uint32_t mant = bits >> 9;
  const float f = __uint_as_float(mant | 0x3f800000u) - 1.0f;  // exact
  const float l1 = mant ? log1pf(f - 1.0f) : -87.33654475055311f;  // ln(u)
  return -__logf(-l1);
}

__device__ __forceinline__ float gumbel_at(uint32_t flat_idx) {
  uint32_t x0 = 0u, x1 = flat_idx;
  threefry2x32_k42(x0, x1);
  return gumbel_from_bits(x0 ^ x1);
}

// order-preserving f32 pack with complemented index (first-occurrence argmax).
__device__ __forceinline__ unsigned long long pack_vn(float v, int n) {
  uint32_t u = __float_as_uint(v);
  u ^= ((uint32_t)((int32_t)u >> 31)) | 0x80000000u;
  return ((unsigned long long)u << 32) | (uint32_t)(0xFFFFFFFFu - (uint32_t)n);
}

__device__ __forceinline__ float unpack_v(unsigned long long p) {
  uint32_t u = (uint32_t)(p >> 32);
  u = (u & 0x80000000u) ? (u ^ 0x80000000u) : ~u;
  return __uint_as_float(u);
}

__device__ __forceinline__ int unpack_n(unsigned long long p) {
  return (int)(0xFFFFFFFFu - (uint32_t)(p & 0xFFFFFFFFull));
}

__device__ __forceinline__ unsigned long long umax64(unsigned long long a,
                                                     unsigned long long b) {
  return a > b ? a : b;
}

// Canonical f32 dot: all exact-path evaluations use THIS chain (consistent).
__device__ __forceinline__ float dot_q_e(const float4* q4, const float4* e4) {
  float s = 0.0f;
#pragma unroll
  for (int k4 = 0; k4 < 16; ++k4) {
    const float4 e = e4[k4];
    const float4 q = q4[k4];
    s = fmaf(q.x, e.x, s);
    s = fmaf(q.y, e.y, s);
    s = fmaf(q.z, e.z, s);
    s = fmaf(q.w, e.w, s);
  }
  return s;
}

// bf16 split helpers (explicit RNE)
__device__ __forceinline__ unsigned short f32_to_bf16_rne(float f) {
  const uint32_t u = __float_as_uint(f);
  return (unsigned short)((u + 0x7fffu + ((u >> 16) & 1u)) >> 16);
}
__device__ __forceinline__ float bf16_to_f32(unsigned short h) {
  return __uint_as_float(((uint32_t)h) << 16);
}

// ---------------- K0a: standalone per-chunk max ||e||_2 (fallback path) -----
__global__ __launch_bounds__(256) void advnet_enorm(const float* __restrict__ emb,
                                                    float* __restrict__ ws) {
  const int c = blockIdx.x;
  const int t = threadIdx.x;
  const int lane = t & 63;
  const int row = t >> 1;
  const int n = c * CHUNK + row;
  float ss = 0.0f;
  if (n < N_COLS) {
    const float4* p = (const float4*)emb + (size_t)n * 16 + (t & 1) * 8;
#pragma unroll
    for (int i = 0; i < 8; ++i) {
      const float4 v = p[i];
      ss = fmaf(v.x, v.x, ss); ss = fmaf(v.y, v.y, ss);
      ss = fmaf(v.z, v.z, ss); ss = fmaf(v.w, v.w, ss);
    }
  }
  ss += __shfl_xor(ss, 1, 64);
  float mx = ss;
  for (int off = 2; off < 64; off <<= 1) mx = fmaxf(mx, __shfl_xor(mx, off, 64));
  __shared__ float sm[4];
  if (lane == 0) sm[t >> 6] = mx;
  __syncthreads();
  if (t == 0)
    ws[WS_ENORM + c] =
        sqrtf(fmaxf(fmaxf(sm[0], sm[1]), fmaxf(sm[2], sm[3]))) * 1.00002f;
}

// ------- K0b: build pre-swizzled bf16 hi/lo tables + fused chunk ||e|| ------
// Table layout per chunk c: 1024 granules of 16B; granule L = row*8 + gz,
// gz = kq ^ (row&7). K1's linear global_load_lds reproduces the swizzled
// LDS layout its ds_reads expect.
__global__ __launch_bounds__(256) void advnet_ebuild(const float* __restrict__ emb,
                                                     float* __restrict__ ws) {
  const int c = blockIdx.x;
  const int t = threadIdx.x;
  char* hi_b = (char*)(ws + WS_EHI) + (size_t)c * 16384;
  char* lo_b = (char*)(ws + WS_ELO) + (size_t)c * 16384;
  float mx = 0.0f;
#pragma unroll
  for (int k = 0; k < 4; ++k) {
    const int j = t + 256 * k;          // source granule 0..1023
    const int row = j >> 3, kq = j & 7;
    const int n = c * CHUNK + row;
    ushort8 hi = (ushort8)0, lo = (ushort8)0;
    float ss = 0.0f;
    if (n < N_COLS) {
      const float4* ep = (const float4*)emb + (size_t)n * 16 + kq * 2;
      const float4 a0 = ep[0], a1 = ep[1];
      const float e[8] = {a0.x, a0.y, a0.z, a0.w, a1.x, a1.y, a1.z, a1.w};
#pragma unroll
      for (int j8 = 0; j8 < 8; ++j8) {
        const unsigned short h = f32_to_bf16_rne(e[j8]);
        hi[j8] = h;
        lo[j8] = f32_to_bf16_rne(e[j8] - bf16_to_f32(h));
        ss = fmaf(e[j8], e[j8], ss);
      }
    }
    const int gz = kq ^ (row & 7);
    *(ushort8*)(hi_b + (size_t)(row * 8 + gz) * 16) = hi;
    *(ushort8*)(lo_b + (size_t)(row * 8 + gz) * 16) = lo;
    // 8 consecutive lanes hold one row's 8 granules (8-aligned, within a wave)
    ss += __shfl_xor(ss, 1, 64);
    ss += __shfl_xor(ss, 2, 64);
    ss += __shfl_xor(ss, 4, 64);
    mx = fmaxf(mx, ss);
  }
  for (int off = 8; off < 64; off <<= 1) mx = fmaxf(mx, __shfl_xor(mx, off, 64));
  __shared__ float sm[4];
  if ((t & 63) == 0) sm[t >> 6] = mx;
  __syncthreads();
  if (t == 0)
    ws[WS_ENORM + c] =
        sqrtf(fmaxf(fmaxf(sm[0], sm[1]), fmaxf(sm[2], sm[3]))) * 1.00002f;
}

// ---- staging helpers for K1 ----
__device__ __forceinline__ void stage_tbl(const char* tb_hi, const char* tb_lo,
                                          unsigned short* eh, unsigned short* el,
                                          int c, int wave, int lane) {
  const size_t cb = (size_t)c * 16384 + (size_t)(wave * 1024 + lane * 16);
  const int wo = wave * 1024;
#pragma unroll
  for (int i = 0; i < 4; ++i) {
    const int off = i * 4096;
    __builtin_amdgcn_global_load_lds(
        (const __attribute__((address_space(1))) void*)(tb_hi + cb + off),
        (__attribute__((address_space(3))) void*)((char*)eh + wo + off), 16, 0, 0);
    __builtin_amdgcn_global_load_lds(
        (const __attribute__((address_space(1))) void*)(tb_lo + cb + off),
        (__attribute__((address_space(3))) void*)((char*)el + wo + off), 16, 0, 0);
  }
}

__device__ __forceinline__ void stage_conv(const float* __restrict__ emb,
                                           unsigned short* eh, unsigned short* el,
                                           int c, int tid) {
  const int n0 = c * CHUNK;
#pragma unroll
  for (int k = 0; k < 4; ++k) {
    const int p = tid + 256 * k;
    const int row = p >> 3, kq = p & 7;
    const int n = n0 + row;
    ushort8 hi = (ushort8)0, lo = (ushort8)0;
    if (n < N_COLS) {
      const float4* ep = (const float4*)emb + (size_t)n * 16 + kq * 2;
      const float4 a0 = ep[0], a1 = ep[1];
      const float e[8] = {a0.x, a0.y, a0.z, a0.w, a1.x, a1.y, a1.z, a1.w};
#pragma unroll
      for (int j = 0; j < 8; ++j) {
        const unsigned short h = f32_to_bf16_rne(e[j]);
        hi[j] = h;
        lo[j] = f32_to_bf16_rne(e[j] - bf16_to_f32(h));
      }
    }
    const int off = row * 64 + ((kq * 8) ^ ((row & 7) << 3));
    *(ushort8*)&eh[off] = hi;
    *(ushort8*)&el[off] = lo;
  }
}

// ------------------------- K1: MFMA GEMM pass -------------------------------
// 2048 blocks, 4 waves. Swizzled block mapping: raw = b8 + 8*(16a + rg),
// strip = 8a + b8 -> all 16 same-strip blocks (rg=0..15) share raw%8 (same
// XCD under round-robin) and are dispatch-adjacent => each 32KB table chunk
// is fetched into one XCD's L2 once and reused 16x (verified: FETCH 35MB, r7).
// Single-buffer LDS (32KB) + __launch_bounds__(256,2): EMPIRICAL hipcc law
// cap = 512/(2*arg): arg2->128-cap (r7: 88 used, no spill); arg4->64-cap
// (r9: spilled 374MB); arg5->48-cap (r8: spilled 662MB). With 88 VGPR the
// HW quantum (m69: waves halve at 64/128) gives 4 waves/SIMD -> 4 blocks/CU
// = 16 waves/CU: r9's TLP without r9's spill traffic.
// q pre-scaled by log2e so the epilogue uses raw exp2 (no mul, no mask).
template <bool TBL>
__global__ __launch_bounds__(256, 2) void advnet_gemm(
    const int* __restrict__ u_id, const int* __restrict__ pos_id,
    const float* __restrict__ emb, float* __restrict__ ws) {
  __shared__ unsigned short eh_s[8192], el_s[8192];

  const int tid = threadIdx.x;
  const int raw = blockIdx.x;
  const int b8 = raw & 7;
  const int rest = raw >> 3;
  const int rg = rest & 15;
  const int strip = b8 + 8 * (rest >> 4);
  const int wave = tid >> 6;
  const int lane = tid & 63;
  const int lc = lane & 15;
  const int lg = lane >> 4;

  // ---- stage q split (scaled by log2e) into eh/el, hoist frags to regs ----
#pragma unroll
  for (int k = 0; k < 4; ++k) {
    const int p = tid + 256 * k;
    const int row = p >> 3, kq = p & 7;
    const int b = rg * 128 + row;
    const float4* ua = (const float4*)emb + (size_t)u_id[b] * 16 + kq * 2;
    const float4* pa = (const float4*)emb + (size_t)pos_id[b] * 16 + kq * 2;
    const float4 a0 = ua[0], a1 = ua[1], c0 = pa[0], c1 = pa[1];
    const float q[8] = {(a0.x + c0.x) * LOG2E_F, (a0.y + c0.y) * LOG2E_F,
                        (a0.z + c0.z) * LOG2E_F, (a0.w + c0.w) * LOG2E_F,
                        (a1.x + c1.x) * LOG2E_F, (a1.y + c1.y) * LOG2E_F,
                        (a1.z + c1.z) * LOG2E_F, (a1.w + c1.w) * LOG2E_F};
    ushort8 hi, lo;
#pragma unroll
    for (int j = 0; j < 8; ++j) {
      const unsigned short h = f32_to_bf16_rne(q[j]);
      hi[j] = h;
      lo[j] = f32_to_bf16_rne(q[j] - bf16_to_f32(h));
    }
    const int off = row * 64 + ((kq * 8) ^ ((row & 7) << 3));
    *(ushort8*)&eh_s[off] = hi;
    *(ushort8*)&el_s[off] = lo;
  }
  __syncthreads();

  short8 qh_r[2][2], ql_r[2][2];  // [kh][rt]
#pragma unroll
  for (int kh = 0; kh < 2; ++kh)
#pragma unroll
    for (int rt = 0; rt < 2; ++rt) {
      const int r = wave * 32 + rt * 16 + lc;
      const int off = r * 64 + (((kh * 4 + lg) * 8) ^ ((r & 7) << 3));
      qh_r[kh][rt] = *(const short8*)&eh_s[off];
      ql_r[kh][rt] = *(const short8*)&el_s[off];
    }
  __syncthreads();  // frag reads done before e staging overwrites

  float m[8], Z[8];
#pragma unroll
  for (int s = 0; s < 8; ++s) { m[s] = NEG_HUGE; Z[s] = 0.0f; }

  const char* tb_hi = (const char*)(ws + WS_EHI);
  const char* tb_lo = (const char*)(ws + WS_ELO);

  for (int c = strip; c < NCHUNK; c += NSTRIPS) {
    if (TBL) stage_tbl(tb_hi, tb_lo, eh_s, el_s, c, wave, lane);
    else     stage_conv(emb, eh_s, el_s, c, tid);
    __syncthreads();  // drains global_load_lds + barrier

    // ---- MFMA: acc = qh*eh + qh*el + ql*eh over K=64 ----
    f32x4 acc[2][8];
#pragma unroll
    for (int rt = 0; rt < 2; ++rt)
#pragma unroll
      for (int ct = 0; ct < 8; ++ct) acc[rt][ct] = (f32x4){0.f, 0.f, 0.f, 0.f};

#pragma unroll
    for (int kh = 0; kh < 2; ++kh) {
#pragma unroll
      for (int ct = 0; ct < 8; ++ct) {
        const int col = ct * 16 + lc;
        const int off = col * 64 + (((kh * 4 + lg) * 8) ^ ((col & 7) << 3));
        const short8 ehf = *(const short8*)&eh_s[off];
        const short8 elf = *(const short8*)&el_s[off];
#pragma unroll
        for (int rt = 0; rt < 2; ++rt) {
          acc[rt][ct] = __builtin_amdgcn_mfma_f32_16x16x32_bf16(qh_r[kh][rt], ehf, acc[rt][ct], 0, 0, 0);
          acc[rt][ct] = __builtin_amdgcn_mfma_f32_16x16x32_bf16(qh_r[kh][rt], elf, acc[rt][ct], 0, 0, 0);
          acc[rt][ct] = __builtin_amdgcn_mfma_f32_16x16x32_bf16(ql_r[kh][rt], ehf, acc[rt][ct], 0, 0, 0);
        }
      }
    }

    // ---- epilogue (log2 space, no mask): online (m,Z) + chunk max ----
    // C layout (m89): col = lane&15, row = (lane>>4)*4 + reg.
#pragma unroll
    for (int rt = 0; rt < 2; ++rt) {
#pragma unroll
      for (int j = 0; j < 4; ++j) {
        const int s = rt * 4 + j;
        float cm = acc[rt][0][j];
#pragma unroll
        for (int ct = 1; ct < 8; ++ct) cm = fmaxf(cm, acc[rt][ct][j]);
        const float nm = fmaxf(m[s], cm);
        float za = 0.0f;
#pragma unroll
        for (int ct = 0; ct < 8; ++ct) za += EXP2F(acc[rt][ct][j] - nm);
        Z[s] = Z[s] * EXP2F(m[s] - nm) + za;
        m[s] = nm;
        float cr = cm;
        cr = fmaxf(cr, __shfl_xor(cr, 1, 64));
        cr = fmaxf(cr, __shfl_xor(cr, 2, 64));
        cr = fmaxf(cr, __shfl_xor(cr, 4, 64));
        cr = fmaxf(cr, __shfl_xor(cr, 8, 64));
        if (lc == 0) {
          const int row = rg * 128 + wave * 32 + rt * 16 + lg * 4 + j;
          ws[WS_CMAX + (size_t)row * NCHUNK + c] = cr;  // log2-scaled
        }
      }
    }
    __syncthreads();  // all LDS reads done before next stage overwrites
  }

  // ---- merge (m,Z) over the 16 lanes sharing each row; write partials ----
#pragma unroll
  for (int rt = 0; rt < 2; ++rt) {
#pragma unroll
    for (int j = 0; j < 4; ++j) {
      const int s = rt * 4 + j;
      float mi = m[s], Zi = Z[s];
      for (int off = 1; off < 16; off <<= 1) {
        const float om = __shfl_xor(mi, off, 64);
        const float oZ = __shfl_xor(Zi, off, 64);
        const float nm = fmaxf(mi, om);
        Zi = Zi * EXP2F(mi - nm) + oZ * EXP2F(om - nm);
        mi = nm;
      }
      if (lc == 0) {
        const int row = rg * 128 + wave * 32 + rt * 16 + lg * 4 + j;
        ws[WS_MPART + (size_t)row * NSTRIPS + strip] = mi;  // log2-scaled
        ws[WS_ZPART + (size_t)row * NSTRIPS + strip] = Zi;
      }
    }
  }
}

// ------- K2: per-row stats + seed winner from argmax chunk -> v_lb ----------
__global__ __launch_bounds__(128) void advnet_rowstat(
    const int* __restrict__ u_id, const int* __restrict__ pos_id,
    const float* __restrict__ emb, float* __restrict__ ws) {
  const int r = blockIdx.x;
  const int t = threadIdx.x;

  __shared__ float sA[2], sB[2];
  __shared__ unsigned long long sP[2];
  __shared__ float qrow[64];

  const size_t idx = (size_t)r * NSTRIPS + t;
  const float ms = ws[WS_MPART + idx];   // log2-scaled
  const float zs = ws[WS_ZPART + idx];
  float Ms = ms;
  for (int off = 1; off < 64; off <<= 1) Ms = fmaxf(Ms, __shfl_xor(Ms, off, 64));
  if ((t & 63) == 0) sA[t >> 6] = Ms;
  __syncthreads();
  Ms = fmaxf(sA[0], sA[1]);
  float z = zs * EXP2F(ms - Ms);
  for (int off = 1; off < 64; off <<= 1) z += __shfl_xor(z, off, 64);
  if ((t & 63) == 0) sB[t >> 6] = z;
  __syncthreads();
  const float Z = sB[0] + sB[1];
  const float M_nat = Ms * LN2_F;        // nat-space anchor

  // ---- c* = chunk containing the (scaled) row max ----
  unsigned long long cp = 0ull;
  for (int c = t; c < NCHUNK; c += 128)
    cp = umax64(cp, pack_vn(ws[WS_CMAX + (size_t)r * NCHUNK + c], c));
  for (int off = 1; off < 64; off <<= 1)
    cp = umax64(cp, __shfl_xor(cp, off, 64));
  if ((t & 63) == 0) sP[t >> 6] = cp;
  __syncthreads();
  cp = umax64(sP[0], sP[1]);
  const int cstar = unpack_n(cp);

  if (t < 16) {
    const float4 a = ((const float4*)emb)[(size_t)u_id[r] * 16 + t];
    const float4 c = ((const float4*)emb)[(size_t)pos_id[r] * 16 + t];
    ((float4*)qrow)[t] = make_float4(a.x + c.x, a.y + c.y, a.z + c.z, a.w + c.w);
  }
  __syncthreads();

  // ---- ||q|| (unscaled, upper-margined) ----
  {
    const float qv = qrow[t & 63];
    float ss = qv * qv;
    for (int off = 1; off < 64; off <<= 1) ss += __shfl_xor(ss, off, 64);
    if (t == 0) ws[WS_QNORM + r] = sqrtf(ss) * 1.00002f;
  }

  // ---- evaluate chunk c* under the HARD bound -> certified v_lb ----
  unsigned long long bp = 0ull;
  const int n = cstar * CHUNK + t;
  if (n < N_COLS) {
    const float s = dot_q_e((const float4*)qrow, (const float4*)emb + (size_t)n * 16);
    if (s != 0.0f && s >= M_nat - G_SPAN_HARD) {
      const uint32_t L = (uint32_t)r * (uint32_t)N_COLS + (uint32_t)n;
      bp = pack_vn(gumbel_at(L) + s, n);
    }
  }
  for (int off = 1; off < 64; off <<= 1)
    bp = umax64(bp, __shfl_xor(bp, off, 64));
  if ((t & 63) == 0) sP[t >> 6] = bp;
  __syncthreads();
  if (t == 0) {
    const unsigned long long best = umax64(sP[0], sP[1]);
    ((unsigned long long*)(ws + WS_BEST))[r] = best;   // seed (reset each call)
    ws[WS_VLB + r] = unpack_v(best);                   // certified lower bound (nat)
    ws[WS_M + r] = M_nat;
    ws[WS_Z + r] = Z;
    ((int*)ws)[WS_CSTAR + r] = cstar;
  }
}

// ---- K3: gumbel-first candidate scan. 2 blocks/row (parity-split chunks). --
// Column n can win only if g_n > v_lb - (cmax_nat_c + bb_c). Gumbels are pure
// VALU -> evaluate them FIRST; canonical f32 dots only for survivors.
#define SVCAP 2048
__global__ __launch_bounds__(256) void advnet_pick(
    const int* __restrict__ u_id, const int* __restrict__ pos_id,
    const float* __restrict__ emb, float* __restrict__ ws) {
  const int r = blockIdx.x >> 1;
  const int par = blockIdx.x & 1;
  const int t = threadIdx.x;

  __shared__ float qrow[64];
  __shared__ unsigned short cq[600];
  __shared__ float cqg[600];
  __shared__ unsigned int svpk[SVCAP];
  __shared__ float svg[SVCAP];
  __shared__ int cqn, svn;
  __shared__ unsigned long long sred[4];

  if (t == 0) { cqn = 0; svn = 0; }
  if (t < 16) {
    const float4 a = ((const float4*)emb)[(size_t)u_id[r] * 16 + t];
    const float4 c = ((const float4*)emb)[(size_t)pos_id[r] * 16 + t];
    ((float4*)qrow)[t] = make_float4(a.x + c.x, a.y + c.y, a.z + c.z, a.w + c.w);
  }
  const float vlb = ws[WS_VLB + r];
  const float bq = ws[WS_QNORM + r] * EPS_B;
  const int cstar = ((const int*)ws)[WS_CSTAR + r];
  __syncthreads();

  // ---- phase 1: candidate chunks of this parity -> LDS queue ----
  for (int c = par + 2 * t; c < NCHUNK; c += 512) {
    if (c == cstar) continue;  // fully covered by K2's seed
    const float cm = ws[WS_CMAX + (size_t)r * NCHUNK + c];  // log2-scaled
    const float gth = vlb - fmaf(cm, LN2_F, bq * ws[WS_ENORM + c]);
    if (gth < G_MAX_MARGIN) {
      const int k = atomicAdd(&cqn, 1);
      cq[k] = (unsigned short)c;   // max 586 per parity < 600
      cqg[k] = gth;
    }
  }
  __syncthreads();
  const int nq = cqn;
  const float4* qr4 = (const float4*)qrow;

  unsigned long long bp = 0ull;

  // ---- phase 2: 8 chunks/iter gumbel filter; drain survivors as needed ----
  for (int base = 0; base < nq; base += 8) {
    if (svn > SVCAP - 1024) {  // uniform decision (svn stable since last sync)
      __syncthreads();
      const int cnt = svn;
      for (int k = t; k < cnt; k += 256) {
        const int n = (int)svpk[k];
        const float s = dot_q_e(qr4, (const float4*)emb + (size_t)n * 16);
        if (s != 0.0f) bp = umax64(bp, pack_vn(svg[k] + s, n));
      }
      __syncthreads();
      if (t == 0) svn = 0;
      __syncthreads();
    }
#pragma unroll
    for (int u = 0; u < 4; ++u) {
      const int idx = t + 256 * u;
      const int slot = base + (idx >> 7);
      if (slot < nq) {
        const int n = (int)cq[slot] * CHUNK + (idx & 127);
        if (n < N_COLS) {
          const float g = gumbel_at((uint32_t)r * (uint32_t)N_COLS + (uint32_t)n);
          if (g > cqg[slot] - G_FILTER_SLACK) {
            const int k = atomicAdd(&svn, 1);
            if (k < SVCAP) { svpk[k] = (unsigned)n; svg[k] = g; }
          }
        }
      }
    }
    __syncthreads();  // pushes visible; svn settled for next-iter check
  }

  // ---- final drain ----
  {
    const int cnt = svn < SVCAP ? svn : SVCAP;
    for (int k = t; k < cnt; k += 256) {
      const int n = (int)svpk[k];
      const float s = dot_q_e(qr4, (const float4*)emb + (size_t)n * 16);
      if (s != 0.0f) bp = umax64(bp, pack_vn(svg[k] + s, n));
    }
  }

  // ---- block reduce + merge into per-row best ----
  for (int off = 1; off < 64; off <<= 1)
    bp = umax64(bp, __shfl_xor(bp, off, 64));
  if ((t & 63) == 0) sred[t >> 6] = bp;
  __syncthreads();
  if (t == 0) {
    const unsigned long long b =
        umax64(umax64(sred[0], sred[1]), umax64(sred[2], sred[3]));
    if (b) atomicMax((unsigned long long*)(ws + WS_BEST) + r, b);
  }
}

// --------------------------- K4: finalize outputs ---------------------------
__global__ __launch_bounds__(64) void advnet_final(
    const int* __restrict__ u_id, const int* __restrict__ pos_id,
    const float* __restrict__ emb, const float* __restrict__ ws,
    float* __restrict__ out) {
  const int r = blockIdx.x * 64 + threadIdx.x;
  if (r >= B_ROWS) return;
  const unsigned long long w = ((const unsigned long long*)(ws + WS_BEST))[r];
  const int n = unpack_n(w);
  const float4* qa = (const float4*)emb + (size_t)u_id[r] * 16;
  const float4* qb = (const float4*)emb + (size_t)pos_id[r] * 16;
  const float4* e4 = (const float4*)emb + (size_t)n * 16;
  float s = 0.0f;
#pragma unroll
  for (int k4 = 0; k4 < 16; ++k4) {
    const float4 a = qa[k4], b = qb[k4], e = e4[k4];
    float4 q;
    q.x = a.x + b.x; q.y = a.y + b.y; q.z = a.z + b.z; q.w = a.w + b.w;
    s = fmaf(q.x, e.x, s);
    s = fmaf(q.y, e.y, s);
    s = fmaf(q.z, e.z, s);
    s = fmaf(q.w, e.w, s);
  }
  out[r] = (float)n;
  out[B_ROWS + r] = __expf(s - ws[WS_M + r]) / ws[WS_Z + r];
}

extern "C" void kernel_launch(void* const* d_in, const int* in_sizes, int n_in,
                              void* d_out, int out_size, void* d_ws, size_t ws_size,
                              hipStream_t stream) {
  const int* u_id = (const int*)d_in[0];
  const int* pos_id = (const int*)d_in[1];
  // d_in[2] = train_mask: unused by the reference output
  const float* emb = (const float*)d_in[3];
  float* ws = (float*)d_ws;
  float* out = (float*)d_out;  // [2048 samples | 2048 probs], f32

  const size_t need = (size_t)WS_END * 4;  // ~47.9 MiB with tables
  const bool tbl = ws_size >= need;        // deterministic across calls

  if (tbl) {
    advnet_ebuild<<<dim3(NCHUNK), dim3(256), 0, stream>>>(emb, ws);  // fused enorm
    advnet_gemm<true><<<dim3(ROWG * NSTRIPS), dim3(256), 0, stream>>>(
        u_id, pos_id, emb, ws);
  } else {
    advnet_enorm<<<dim3(NCHUNK), dim3(256), 0, stream>>>(emb, ws);
    advnet_gemm<false><<<dim3(ROWG * NSTRIPS), dim3(256), 0, stream>>>(
        u_id, pos_id, emb, ws);
  }
  advnet_rowstat<<<dim3(B_ROWS), dim3(128), 0, stream>>>(u_id, pos_id, emb, ws);
  advnet_pick<<<dim3(B_ROWS * 2), dim3(256), 0, stream>>>(u_id, pos_id, emb, ws);
  advnet_final<<<dim3(B_ROWS / 64), dim3(64), 0, stream>>>(u_id, pos_id, emb, ws, out);
}